// Round 1
// baseline (1208.978 us; speedup 1.0000x reference)
//
#include <hip/hip_runtime.h>
#include <math.h>

#define B 8
#define N 4096
#define C 64
#define D 64
#define K 16

// ---------------------------------------------------------------------------
// Kernel 0: per-row squared norms, numpy-pairwise-like order (8 accumulators)
// ---------------------------------------------------------------------------
__global__ __launch_bounds__(256)
void sqnorm_kernel(const float* __restrict__ F, float* __restrict__ sq) {
    int row = blockIdx.x * blockDim.x + threadIdx.x;
    if (row >= B * N) return;
    const float* f = F + (size_t)row * C;
    float r[8];
    #pragma unroll
    for (int j = 0; j < 8; j++) { float t = f[j]; r[j] = t * t; }
    #pragma unroll
    for (int m = 1; m < 8; m++) {
        #pragma unroll
        for (int j = 0; j < 8; j++) { float t = f[8 * m + j]; r[j] = fmaf(t, t, r[j]); }
    }
    sq[row] = ((r[0] + r[1]) + (r[2] + r[3])) + ((r[4] + r[5]) + (r[6] + r[7]));
}

// ---------------------------------------------------------------------------
// Kernel 1: KNN — 64 queries/block, stream over 64-candidate tiles.
// 256 threads: dot tile via 4x4 register tiling; top-16 kept in registers as
// 4 partial lists per row (thread (row, quarter)), merged once at the end.
// ---------------------------------------------------------------------------
__global__ __launch_bounds__(256)
void knn_kernel(const float* __restrict__ F, const float* __restrict__ sqg,
                int* __restrict__ knn) {
    const int b  = blockIdx.y;
    const int i0 = blockIdx.x * 64;
    const float* Fb  = F   + (size_t)b * N * C;
    const float* sqb = sqg + (size_t)b * N;

    __shared__ float Qs[64][68];   // stride 68 dwords: float4-aligned rows
    __shared__ float Cs[64][68];
    __shared__ float d2t[64][66];  // transposed d2: [col][row], stride 66
    __shared__ float sqQ[64];
    __shared__ float sqC[64];

    const int tid = threadIdx.x;
    const int lr  = tid >> 2;          // load row 0..63
    const int lc  = (tid & 3) * 4;     // load float4 base 0/4/8/12

    {   // Q tile
        const float4* src = (const float4*)(Fb + (size_t)(i0 + lr) * C);
        #pragma unroll
        for (int m = 0; m < 4; m++) {
            float4 v = src[lc + m];
            *(float4*)&Qs[lr][(lc + m) * 4] = v;
        }
    }
    if (tid < 64) sqQ[tid] = sqb[i0 + tid];

    // per-thread partial top-16 (registers, compile-time indexed only)
    float bd[K]; int bi[K];
    #pragma unroll
    for (int k = 0; k < K; k++) { bd[k] = INFINITY; bi[k] = 0x7FFFFFFF; }
    float worst = INFINITY; int wpos = 0;

    const int tx   = tid & 15;   // dot-tile col group
    const int ty   = tid >> 4;   // dot-tile row group (rows ty*4..+3)
    const int srow = tid & 63;   // scan row
    const int sq4  = tid >> 6;   // scan quarter (cols sq4*16..+15)

    for (int j0 = 0; j0 < N; j0 += 64) {
        __syncthreads();  // previous scan finished before Cs/d2t overwrite
        {   // candidate tile
            const float4* src = (const float4*)(Fb + (size_t)(j0 + lr) * C);
            #pragma unroll
            for (int m = 0; m < 4; m++) {
                float4 v = src[lc + m];
                *(float4*)&Cs[lr][(lc + m) * 4] = v;
            }
        }
        if (tid < 64) sqC[tid] = sqb[j0 + tid];
        __syncthreads();

        // 64x64 dot tile; thread -> rows {ty*4+rr}, cols {tx+16*cc}
        float acc[4][4];
        #pragma unroll
        for (int rr = 0; rr < 4; rr++)
            #pragma unroll
            for (int cc = 0; cc < 4; cc++) acc[rr][cc] = 0.0f;

        for (int c4 = 0; c4 < 16; c4++) {
            float4 q[4], p[4];
            #pragma unroll
            for (int rr = 0; rr < 4; rr++) q[rr] = *(const float4*)&Qs[ty * 4 + rr][c4 * 4];
            #pragma unroll
            for (int cc = 0; cc < 4; cc++) p[cc] = *(const float4*)&Cs[tx + 16 * cc][c4 * 4];
            #pragma unroll
            for (int rr = 0; rr < 4; rr++) {
                #pragma unroll
                for (int cc = 0; cc < 4; cc++) {
                    acc[rr][cc] = fmaf(q[rr].x, p[cc].x, acc[rr][cc]);
                    acc[rr][cc] = fmaf(q[rr].y, p[cc].y, acc[rr][cc]);
                    acc[rr][cc] = fmaf(q[rr].z, p[cc].z, acc[rr][cc]);
                    acc[rr][cc] = fmaf(q[rr].w, p[cc].w, acc[rr][cc]);
                }
            }
        }

        #pragma unroll
        for (int rr = 0; rr < 4; rr++) {
            #pragma unroll
            for (int cc = 0; cc < 4; cc++) {
                int r = ty * 4 + rr, col = tx + 16 * cc;
                float dv = sqQ[r] + sqC[col] - 2.0f * acc[rr][cc];
                if (i0 + r == j0 + col) dv = INFINITY;   // mask diagonal
                d2t[col][r] = dv;
            }
        }
        __syncthreads();

        // streaming top-16 update: 4 threads per row, 16 cols each
        #pragma unroll
        for (int jj = 0; jj < 16; jj++) {
            int col = sq4 * 16 + jj;
            float dv = d2t[col][srow];   // lanes read consecutive dwords: conflict-free
            if (dv < worst) {            // strict <: keeps earlier (lower) index on ties
                int id = j0 + col;
                #pragma unroll
                for (int k = 0; k < K; k++) if (k == wpos) { bd[k] = dv; bi[k] = id; }
                worst = bd[0]; wpos = 0; int wid = bi[0];
                #pragma unroll
                for (int k = 1; k < K; k++) {
                    if (bd[k] > worst || (bd[k] == worst && bi[k] > wid)) {
                        worst = bd[k]; wpos = k; wid = bi[k];
                    }
                }
            }
        }
    }
    __syncthreads();

    // dump partials: d2t[row][q*16+k] = value, Cs (as int) = id
    #pragma unroll
    for (int k = 0; k < K; k++) {
        d2t[srow][sq4 * 16 + k] = bd[k];
        ((int*)&Cs[0][0])[srow * 68 + sq4 * 16 + k] = bi[k];
    }
    __syncthreads();

    // merge: one thread per row, 16 extract-mins over 64 entries
    if (tid < 64) {
        int outids[K];
        #pragma unroll
        for (int k = 0; k < K; k++) {
            float best = INFINITY; int bestid = 0x7FFFFFFF; int bpos = 0;
            for (int e = 0; e < 64; e++) {
                float v  = d2t[tid][e];
                int   id = ((int*)&Cs[0][0])[tid * 68 + e];
                if (v < best || (v == best && id < bestid)) { best = v; bestid = id; bpos = e; }
            }
            outids[k] = bestid;
            d2t[tid][bpos] = INFINITY;
        }
        int* dst = knn + ((size_t)b * N + i0 + tid) * K;
        #pragma unroll
        for (int k = 0; k < K; k++) dst[k] = outids[k];
    }
}

// ---------------------------------------------------------------------------
// Kernel 2: gather + 2-layer MLP + max over K. One wave (64 lanes) per query;
// lane t owns output channel t. central@W1_top computed once per query.
// ---------------------------------------------------------------------------
__device__ __forceinline__ float gelu_exact(float x) {
    return 0.5f * x * (1.0f + erff(x * 0.70710678118654752440f));
}

__global__ __launch_bounds__(256)
void edgeconv_mlp_kernel(const float* __restrict__ F, const int* __restrict__ knn,
                         const float* __restrict__ W1, const float* __restrict__ b1,
                         const float* __restrict__ W2, const float* __restrict__ b2,
                         float* __restrict__ out) {
    __shared__ float4 nd4[4][K][16];   // neighbor - central, per wave
    __shared__ float4 h14[4][K][16];   // layer-1 activations, per wave
    __shared__ float  cs[4][64];       // central features, per wave

    const int tid = threadIdx.x;
    const int w   = tid >> 6;          // wave in block
    const int t   = tid & 63;          // channel
    const int qi  = blockIdx.x * 4 + w;
    const int b   = qi >> 12;          // qi / N
    const int i   = qi & (N - 1);
    const float* Fb = F + (size_t)b * N * C;

    float ct = Fb[(size_t)i * C + t];
    cs[w][t] = ct;

    int ids[K];
    const int* kp = knn + (size_t)qi * K;
    #pragma unroll
    for (int k = 0; k < K; k++) ids[k] = kp[k];

    #pragma unroll
    for (int k = 0; k < K; k++) {
        float v = Fb[(size_t)ids[k] * C + t];    // coalesced gather row
        ((float*)&nd4[w][k][0])[t] = v - ct;
    }
    __syncthreads();

    // s0[t] = b1[t] + central . W1[0:64, t]  (shared by all K edges)
    float s0a = b1[t], s0b = 0.f, s0c = 0.f, s0d = 0.f;
    for (int c = 0; c < C; c += 4) {
        s0a = fmaf(cs[w][c + 0], W1[(c + 0) * D + t], s0a);
        s0b = fmaf(cs[w][c + 1], W1[(c + 1) * D + t], s0b);
        s0c = fmaf(cs[w][c + 2], W1[(c + 2) * D + t], s0c);
        s0d = fmaf(cs[w][c + 3], W1[(c + 3) * D + t], s0d);
    }
    float s0 = (s0a + s0b) + (s0c + s0d);

    float acc[K];
    #pragma unroll
    for (int k = 0; k < K; k++) acc[k] = s0;

    // layer 1: += (nbr-central) . W1[64:128, t]
    for (int c4 = 0; c4 < 16; c4++) {
        float wa = W1[(C + c4 * 4 + 0) * D + t];
        float wb = W1[(C + c4 * 4 + 1) * D + t];
        float wc = W1[(C + c4 * 4 + 2) * D + t];
        float wd = W1[(C + c4 * 4 + 3) * D + t];
        #pragma unroll
        for (int k = 0; k < K; k++) {
            float4 nv = nd4[w][k][c4];             // wave-uniform addr: broadcast
            acc[k] = fmaf(nv.x, wa, acc[k]);
            acc[k] = fmaf(nv.y, wb, acc[k]);
            acc[k] = fmaf(nv.z, wc, acc[k]);
            acc[k] = fmaf(nv.w, wd, acc[k]);
        }
    }
    #pragma unroll
    for (int k = 0; k < K; k++) {
        ((float*)&h14[w][k][0])[t] = gelu_exact(acc[k]);
    }
    __syncthreads();

    // layer 2 + max over k
    float acc2[K];
    float bb = b2[t];
    #pragma unroll
    for (int k = 0; k < K; k++) acc2[k] = bb;
    for (int c4 = 0; c4 < 16; c4++) {
        float wa = W2[(c4 * 4 + 0) * D + t];
        float wb = W2[(c4 * 4 + 1) * D + t];
        float wc = W2[(c4 * 4 + 2) * D + t];
        float wd = W2[(c4 * 4 + 3) * D + t];
        #pragma unroll
        for (int k = 0; k < K; k++) {
            float4 hv = h14[w][k][c4];
            acc2[k] = fmaf(hv.x, wa, acc2[k]);
            acc2[k] = fmaf(hv.y, wb, acc2[k]);
            acc2[k] = fmaf(hv.z, wc, acc2[k]);
            acc2[k] = fmaf(hv.w, wd, acc2[k]);
        }
    }
    float m = -INFINITY;
    #pragma unroll
    for (int k = 0; k < K; k++) m = fmaxf(m, gelu_exact(acc2[k]));

    out[(size_t)qi * D + t] = m;
}

// ---------------------------------------------------------------------------
extern "C" void kernel_launch(void* const* d_in, const int* in_sizes, int n_in,
                              void* d_out, int out_size, void* d_ws, size_t ws_size,
                              hipStream_t stream) {
    const float* F  = (const float*)d_in[0];
    const float* W1 = (const float*)d_in[1];
    const float* b1 = (const float*)d_in[2];
    const float* W2 = (const float*)d_in[3];
    const float* b2 = (const float*)d_in[4];
    float* out = (float*)d_out;

    float* sq  = (float*)d_ws;                                  // B*N floats
    int*   knn = (int*)((char*)d_ws + (size_t)B * N * sizeof(float)); // B*N*K ints

    sqnorm_kernel<<<dim3((B * N + 255) / 256), 256, 0, stream>>>(F, sq);
    knn_kernel<<<dim3(N / 64, B), 256, 0, stream>>>(F, sq, knn);
    edgeconv_mlp_kernel<<<dim3(B * N / 4), 256, 0, stream>>>(F, knn, W1, b1, W2, b2, out);
}

// Round 3
// 714.868 us; speedup vs baseline: 1.6912x; 1.6912x over previous
//
#include <hip/hip_runtime.h>
#include <math.h>
#include <stdint.h>

#define B 8
#define N 4096
#define C 64
#define D 64
#define K 16

typedef __attribute__((ext_vector_type(8))) short short8;
typedef __attribute__((ext_vector_type(4))) float f32x4;

// ---------------------------------------------------------------------------
// bf16 helpers
// ---------------------------------------------------------------------------
__device__ __forceinline__ unsigned short f2bf(float x) {
    unsigned u = __float_as_uint(x);
    unsigned r = (u + 0x7FFFu + ((u >> 16) & 1u)) >> 16;   // RNE
    return (unsigned short)r;
}
__device__ __forceinline__ float bf2f(unsigned short h) {
    return __uint_as_float(((unsigned)h) << 16);
}

// ---------------------------------------------------------------------------
// Kernel 0: per-row sqnorm (round-1 arithmetic, passed) + 3-term bf16 split
// planes hi/mid/lo: x = hi + mid + lo + O(2^-28)
// ---------------------------------------------------------------------------
__global__ __launch_bounds__(256)
void prep_kernel(const float* __restrict__ F, float* __restrict__ sq,
                 unsigned short* __restrict__ HP, unsigned short* __restrict__ MP,
                 unsigned short* __restrict__ LP) {
    const int row = blockIdx.x * 256 + threadIdx.x;
    const float4* src = (const float4*)(F + (size_t)row * C);
    float4 v[16];
    #pragma unroll
    for (int q = 0; q < 16; q++) v[q] = src[q];

    // sq: identical order to the round-1 kernel that passed
    {
        float r[8];
        #pragma unroll
        for (int j = 0; j < 8; j++) {
            float t = ((const float*)v)[j];
            r[j] = t * t;
        }
        #pragma unroll
        for (int m = 1; m < 8; m++) {
            #pragma unroll
            for (int j = 0; j < 8; j++) {
                float t = ((const float*)v)[8 * m + j];
                r[j] = fmaf(t, t, r[j]);
            }
        }
        sq[row] = ((r[0] + r[1]) + (r[2] + r[3])) + ((r[4] + r[5]) + (r[6] + r[7]));
    }

    uint4* dh = (uint4*)(HP + (size_t)row * C);
    uint4* dm = (uint4*)(MP + (size_t)row * C);
    uint4* dl = (uint4*)(LP + (size_t)row * C);
    #pragma unroll
    for (int c4 = 0; c4 < 4; c4++) {           // 16 values per chunk
        unsigned hu[4], mu[4], lu[4];
        #pragma unroll
        for (int e = 0; e < 4; e++) {
            // wait: 16 values -> 8 packed uints; do 2 sub-chunks of 8
            hu[e] = 0; mu[e] = 0; lu[e] = 0;
        }
        #pragma unroll
        for (int s = 0; s < 2; s++) {
            unsigned hq[4], mq[4], lq[4];
            #pragma unroll
            for (int e = 0; e < 4; e++) {
                float x0 = ((const float*)&v[c4 * 4 + s * 2])[2 * e];
                float x1 = ((const float*)&v[c4 * 4 + s * 2])[2 * e + 1];
                unsigned short h0 = f2bf(x0), h1 = f2bf(x1);
                float r10 = x0 - bf2f(h0), r11 = x1 - bf2f(h1);
                unsigned short m0 = f2bf(r10), m1 = f2bf(r11);
                float r20 = r10 - bf2f(m0), r21 = r11 - bf2f(m1);
                unsigned short l0 = f2bf(r20), l1 = f2bf(r21);
                hq[e] = (unsigned)h0 | ((unsigned)h1 << 16);
                mq[e] = (unsigned)m0 | ((unsigned)m1 << 16);
                lq[e] = (unsigned)l0 | ((unsigned)l1 << 16);
            }
            dh[c4 * 2 + s] = make_uint4(hq[0], hq[1], hq[2], hq[3]);
            dm[c4 * 2 + s] = make_uint4(mq[0], mq[1], mq[2], mq[3]);
            dl[c4 * 2 + s] = make_uint4(lq[0], lq[1], lq[2], lq[3]);
        }
    }
}

// ---------------------------------------------------------------------------
// Kernel 1: MFMA KNN, 3-term split. Block = 64 queries / 4 waves.
// A = candidates, B = queries; lane owns 1 query x 16 cands per tile.
// g = acc_hh + acc_corr; streaming top-16 as sorted u64 keys (d2bits<<32|idx).
// ---------------------------------------------------------------------------
__global__ __launch_bounds__(256)
void knn_mfma_kernel(const unsigned short* __restrict__ HP,
                     const unsigned short* __restrict__ MP,
                     const unsigned short* __restrict__ LP,
                     const float* __restrict__ sqg, int* __restrict__ knn) {
    __shared__ __align__(16) char lds[49152];
    char* Qh = lds;             // 8KB each: 64 rows x 128B, XOR-swizzled
    char* Qm = lds + 8192;
    char* Ql = lds + 16384;
    char* Ch = lds + 24576;
    char* Cm = lds + 32768;
    char* Cl = lds + 40960;

    const int b  = blockIdx.y;
    const int i0 = blockIdx.x * 64;
    const unsigned short* Hb = HP + (size_t)b * N * C;
    const unsigned short* Mb = MP + (size_t)b * N * C;
    const unsigned short* Lb = LP + (size_t)b * N * C;
    const float* sqb = sqg + (size_t)b * N;

    const int tid = threadIdx.x;
    const int l   = tid & 63;
    const int w   = tid >> 6;

    // staging geometry: thread -> row lr, channel group lq (16 ch = 32B)
    const int lr  = tid >> 2;
    const int lq  = tid & 3;
    const int swzW = (lr & 7) << 4;
    const int wb0 = (lr * 128 + lq * 32) ^ swzW;
    const int wb1 = (lr * 128 + lq * 32 + 16) ^ swzW;

    {   // stage Q planes once
        const uint4* sh = (const uint4*)(Hb + (size_t)(i0 + lr) * C + lq * 16);
        const uint4* sm = (const uint4*)(Mb + (size_t)(i0 + lr) * C + lq * 16);
        const uint4* sl = (const uint4*)(Lb + (size_t)(i0 + lr) * C + lq * 16);
        uint4 a0 = sh[0], a1 = sh[1], c0 = sm[0], c1 = sm[1], e0 = sl[0], e1 = sl[1];
        *(uint4*)(Qh + wb0) = a0; *(uint4*)(Qh + wb1) = a1;
        *(uint4*)(Qm + wb0) = c0; *(uint4*)(Qm + wb1) = c1;
        *(uint4*)(Ql + wb0) = e0; *(uint4*)(Ql + wb1) = e1;
    }
    __syncthreads();

    // B fragments (query), register-resident for the whole scan
    const int koff = (l >> 4) * 16;
    const int swzR = (l & 7) << 4;
    const int qrow = w * 16 + (l & 15);
    const int qb0 = (qrow * 128 + koff) ^ swzR;
    const int qb1 = (qrow * 128 + 64 + koff) ^ swzR;
    short8 bh0 = *(const short8*)(Qh + qb0), bh1 = *(const short8*)(Qh + qb1);
    short8 bm0 = *(const short8*)(Qm + qb0), bm1 = *(const short8*)(Qm + qb1);
    short8 bl0 = *(const short8*)(Ql + qb0), bl1 = *(const short8*)(Ql + qb1);

    const float sqq   = sqb[i0 + qrow];
    const int   qglob = i0 + qrow;
    const int   crow0 = (l >> 4) * 4;

    uint64_t bd[16];
    #pragma unroll
    for (int k = 0; k < 16; k++) bd[k] = ~0ull;

    // prefetch tile 0
    uint4 ph0, ph1, pm0, pm1, pl0, pl1;
    {
        const uint4* sh = (const uint4*)(Hb + (size_t)lr * C + lq * 16);
        const uint4* sm = (const uint4*)(Mb + (size_t)lr * C + lq * 16);
        const uint4* sl = (const uint4*)(Lb + (size_t)lr * C + lq * 16);
        ph0 = sh[0]; ph1 = sh[1]; pm0 = sm[0]; pm1 = sm[1]; pl0 = sl[0]; pl1 = sl[1];
    }

    for (int t = 0; t < 64; t++) {
        const int j0 = t * 64;
        __syncthreads();                       // prior tile's frag reads done
        *(uint4*)(Ch + wb0) = ph0; *(uint4*)(Ch + wb1) = ph1;
        *(uint4*)(Cm + wb0) = pm0; *(uint4*)(Cm + wb1) = pm1;
        *(uint4*)(Cl + wb0) = pl0; *(uint4*)(Cl + wb1) = pl1;
        if (t < 63) {
            const uint4* sh = (const uint4*)(Hb + (size_t)(j0 + 64 + lr) * C + lq * 16);
            const uint4* sm = (const uint4*)(Mb + (size_t)(j0 + 64 + lr) * C + lq * 16);
            const uint4* sl = (const uint4*)(Lb + (size_t)(j0 + 64 + lr) * C + lq * 16);
            ph0 = sh[0]; ph1 = sh[1]; pm0 = sm[0]; pm1 = sm[1]; pl0 = sl[0]; pl1 = sl[1];
        }
        __syncthreads();

        float4 sqm0 = *(const float4*)(sqb + j0 +      crow0);
        float4 sqm1 = *(const float4*)(sqb + j0 + 16 + crow0);
        float4 sqm2 = *(const float4*)(sqb + j0 + 32 + crow0);
        float4 sqm3 = *(const float4*)(sqb + j0 + 48 + crow0);

        #pragma unroll
        for (int m = 0; m < 4; m++) {
            const int arow = m * 16 + (l & 15);
            const int ab0 = (arow * 128 + koff) ^ swzR;
            const int ab1 = (arow * 128 + 64 + koff) ^ swzR;
            short8 ah0 = *(const short8*)(Ch + ab0), ah1 = *(const short8*)(Ch + ab1);
            short8 am0 = *(const short8*)(Cm + ab0), am1 = *(const short8*)(Cm + ab1);
            short8 al0 = *(const short8*)(Cl + ab0), al1 = *(const short8*)(Cl + ab1);

            f32x4 accc = {0.f, 0.f, 0.f, 0.f};          // correction terms (small)
            accc = __builtin_amdgcn_mfma_f32_16x16x32_bf16(am0, bm0, accc, 0, 0, 0);
            accc = __builtin_amdgcn_mfma_f32_16x16x32_bf16(am1, bm1, accc, 0, 0, 0);
            accc = __builtin_amdgcn_mfma_f32_16x16x32_bf16(ah0, bl0, accc, 0, 0, 0);
            accc = __builtin_amdgcn_mfma_f32_16x16x32_bf16(ah1, bl1, accc, 0, 0, 0);
            accc = __builtin_amdgcn_mfma_f32_16x16x32_bf16(al0, bh0, accc, 0, 0, 0);
            accc = __builtin_amdgcn_mfma_f32_16x16x32_bf16(al1, bh1, accc, 0, 0, 0);
            accc = __builtin_amdgcn_mfma_f32_16x16x32_bf16(ah0, bm0, accc, 0, 0, 0);
            accc = __builtin_amdgcn_mfma_f32_16x16x32_bf16(ah1, bm1, accc, 0, 0, 0);
            accc = __builtin_amdgcn_mfma_f32_16x16x32_bf16(am0, bh0, accc, 0, 0, 0);
            accc = __builtin_amdgcn_mfma_f32_16x16x32_bf16(am1, bh1, accc, 0, 0, 0);
            f32x4 acch = {0.f, 0.f, 0.f, 0.f};          // hi*hi (dominant)
            acch = __builtin_amdgcn_mfma_f32_16x16x32_bf16(ah0, bh0, acch, 0, 0, 0);
            acch = __builtin_amdgcn_mfma_f32_16x16x32_bf16(ah1, bh1, acch, 0, 0, 0);

            float4 sqm = (m == 0) ? sqm0 : (m == 1) ? sqm1 : (m == 2) ? sqm2 : sqm3;
            #pragma unroll
            for (int r = 0; r < 4; r++) {
                const int cg = j0 + m * 16 + crow0 + r;
                float sqc = (r == 0) ? sqm.x : (r == 1) ? sqm.y : (r == 2) ? sqm.z : sqm.w;
                float g  = acch[r] + accc[r];
                float d2 = fmaf(-2.0f, g, sqq + sqc);   // same single-round as ref
                if (cg == qglob) d2 = INFINITY;
                d2 = fmaxf(d2, 0.0f);
                uint64_t key = ((uint64_t)__float_as_uint(d2) << 32) | (unsigned)cg;
                if (key < bd[15]) {
                    bool c[16];
                    #pragma unroll
                    for (int k = 0; k < 16; k++) c[k] = key < bd[k];
                    #pragma unroll
                    for (int k = 15; k >= 1; --k)
                        bd[k] = c[k - 1] ? bd[k - 1] : (c[k] ? key : bd[k]);
                    bd[0] = c[0] ? key : bd[0];
                }
            }
        }
    }

    // merge 4 sorted lists per query
    __syncthreads();
    uint64_t* keys = (uint64_t*)lds;           // 32KB reuse
    {
        const int qloc = w * 16 + (l & 15);
        const int s    = l >> 4;
        const int base = (qloc * 4 + s) * 16;
        #pragma unroll
        for (int k = 0; k < 16; k++) keys[base + k] = bd[k];
    }
    __syncthreads();
    if (tid < 64) {
        const uint64_t* K0 = keys + (tid * 4 + 0) * 16;
        const uint64_t* K1 = keys + (tid * 4 + 1) * 16;
        const uint64_t* K2 = keys + (tid * 4 + 2) * 16;
        const uint64_t* K3 = keys + (tid * 4 + 3) * 16;
        int p0 = 0, p1 = 0, p2 = 0, p3 = 0;
        uint64_t h0 = K0[0], h1 = K1[0], h2 = K2[0], h3 = K3[0];
        int* dst = knn + ((size_t)b * N + i0 + tid) * K;
        for (int k = 0; k < K; k++) {
            uint64_t m01 = h0 < h1 ? h0 : h1;
            uint64_t m23 = h2 < h3 ? h2 : h3;
            uint64_t mv  = m01 < m23 ? m01 : m23;
            dst[k] = (int)(mv & 0xFFFFFFFFu);
            if      (mv == h0) { ++p0; h0 = (p0 < 16) ? K0[p0] : ~0ull; }
            else if (mv == h1) { ++p1; h1 = (p1 < 16) ? K1[p1] : ~0ull; }
            else if (mv == h2) { ++p2; h2 = (p2 < 16) ? K2[p2] : ~0ull; }
            else               { ++p3; h3 = (p3 < 16) ? K3[p3] : ~0ull; }
        }
    }
}

// ---------------------------------------------------------------------------
// Kernel 2: gather + 2-layer MLP + max over K (unchanged — passed round 1)
// ---------------------------------------------------------------------------
__device__ __forceinline__ float gelu_exact(float x) {
    return 0.5f * x * (1.0f + erff(x * 0.70710678118654752440f));
}

__global__ __launch_bounds__(256)
void edgeconv_mlp_kernel(const float* __restrict__ F, const int* __restrict__ knn,
                         const float* __restrict__ W1, const float* __restrict__ b1,
                         const float* __restrict__ W2, const float* __restrict__ b2,
                         float* __restrict__ out) {
    __shared__ float4 nd4[4][K][16];
    __shared__ float4 h14[4][K][16];
    __shared__ float  cs[4][64];

    const int tid = threadIdx.x;
    const int w   = tid >> 6;
    const int t   = tid & 63;
    const int qi  = blockIdx.x * 4 + w;
    const int b   = qi >> 12;
    const int i   = qi & (N - 1);
    const float* Fb = F + (size_t)b * N * C;

    float ct = Fb[(size_t)i * C + t];
    cs[w][t] = ct;

    int ids[K];
    const int* kp = knn + (size_t)qi * K;
    #pragma unroll
    for (int k = 0; k < K; k++) ids[k] = kp[k];

    #pragma unroll
    for (int k = 0; k < K; k++) {
        float v = Fb[(size_t)ids[k] * C + t];
        ((float*)&nd4[w][k][0])[t] = v - ct;
    }
    __syncthreads();

    float s0a = b1[t], s0b = 0.f, s0c = 0.f, s0d = 0.f;
    for (int c = 0; c < C; c += 4) {
        s0a = fmaf(cs[w][c + 0], W1[(c + 0) * D + t], s0a);
        s0b = fmaf(cs[w][c + 1], W1[(c + 1) * D + t], s0b);
        s0c = fmaf(cs[w][c + 2], W1[(c + 2) * D + t], s0c);
        s0d = fmaf(cs[w][c + 3], W1[(c + 3) * D + t], s0d);
    }
    float s0 = (s0a + s0b) + (s0c + s0d);

    float acc[K];
    #pragma unroll
    for (int k = 0; k < K; k++) acc[k] = s0;

    for (int c4 = 0; c4 < 16; c4++) {
        float wa = W1[(C + c4 * 4 + 0) * D + t];
        float wb = W1[(C + c4 * 4 + 1) * D + t];
        float wc = W1[(C + c4 * 4 + 2) * D + t];
        float wd = W1[(C + c4 * 4 + 3) * D + t];
        #pragma unroll
        for (int k = 0; k < K; k++) {
            float4 nv = nd4[w][k][c4];
            acc[k] = fmaf(nv.x, wa, acc[k]);
            acc[k] = fmaf(nv.y, wb, acc[k]);
            acc[k] = fmaf(nv.z, wc, acc[k]);
            acc[k] = fmaf(nv.w, wd, acc[k]);
        }
    }
    #pragma unroll
    for (int k = 0; k < K; k++) {
        ((float*)&h14[w][k][0])[t] = gelu_exact(acc[k]);
    }
    __syncthreads();

    float acc2[K];
    float bb = b2[t];
    #pragma unroll
    for (int k = 0; k < K; k++) acc2[k] = bb;
    for (int c4 = 0; c4 < 16; c4++) {
        float wa = W2[(c4 * 4 + 0) * D + t];
        float wb = W2[(c4 * 4 + 1) * D + t];
        float wc = W2[(c4 * 4 + 2) * D + t];
        float wd = W2[(c4 * 4 + 3) * D + t];
        #pragma unroll
        for (int k = 0; k < K; k++) {
            float4 hv = h14[w][k][c4];
            acc2[k] = fmaf(hv.x, wa, acc2[k]);
            acc2[k] = fmaf(hv.y, wb, acc2[k]);
            acc2[k] = fmaf(hv.z, wc, acc2[k]);
            acc2[k] = fmaf(hv.w, wd, acc2[k]);
        }
    }
    float m = -INFINITY;
    #pragma unroll
    for (int k = 0; k < K; k++) m = fmaxf(m, gelu_exact(acc2[k]));

    out[(size_t)qi * D + t] = m;
}

// ---------------------------------------------------------------------------
extern "C" void kernel_launch(void* const* d_in, const int* in_sizes, int n_in,
                              void* d_out, int out_size, void* d_ws, size_t ws_size,
                              hipStream_t stream) {
    const float* F  = (const float*)d_in[0];
    const float* W1 = (const float*)d_in[1];
    const float* b1 = (const float*)d_in[2];
    const float* W2 = (const float*)d_in[3];
    const float* b2 = (const float*)d_in[4];
    float* out = (float*)d_out;

    char* ws = (char*)d_ws;
    float*          sq  = (float*)ws;                         // 128 KB
    int*            knn = (int*)(ws + (128 << 10));           // 2 MB
    unsigned short* HP  = (unsigned short*)(ws + (2176 << 10));   // 4 MB
    unsigned short* MP  = (unsigned short*)(ws + (6272 << 10));   // 4 MB
    unsigned short* LP  = (unsigned short*)(ws + (10368 << 10));  // 4 MB

    prep_kernel<<<dim3(B * N / 256), 256, 0, stream>>>(F, sq, HP, MP, LP);
    knn_mfma_kernel<<<dim3(N / 64, B), 256, 0, stream>>>(HP, MP, LP, sq, knn);
    edgeconv_mlp_kernel<<<dim3(B * N / 4), 256, 0, stream>>>(F, knn, W1, b1, W2, b2, out);
}